// Round 1
// baseline (294.173 us; speedup 1.0000x reference)
//
#include <hip/hip_runtime.h>
#include <hip/hip_bf16.h>
#include <math.h>

// Sizes (fixed by the problem)
#define BATCH 16
#define TLEN  512
#define HD    16     // per-direction hidden
#define HID   32     // 2*HD

typedef float v2f __attribute__((ext_vector_type(2)));

// Static device scratch — avoids any assumption about ws_size.
// All arrays fully written before read each call; g_cnt/g_accum are zero-init
// .bss and restored to 0 by the last-arriver block each call.
__device__ float g_outBT[BATCH * TLEN * HID];   // 1 MB
__device__ float g_preA [BATCH * TLEN * HID];   // 1 MB
__device__ float g_Ct   [BATCH * HID * TLEN];   // 1 MB
__device__ float g_un   [BATCH * TLEN];
__device__ float g_w2d  [BATCH * TLEN];
__device__ float g_accum[BATCH];                // zero-initialized, self-resetting
__device__ int   g_cnt  [BATCH];                // zero-initialized, self-resetting

__device__ __forceinline__ float sigm_(float x) {
    return 1.0f / (1.0f + __expf(-x));
}
__device__ __forceinline__ float tanh_(float x) {
    float e = __expf(2.0f * x);
    return 1.0f - 2.0f / (e + 1.0f);
}

__device__ __forceinline__ v2f pk_fma(v2f a, v2f b, v2f c) {
#if __has_builtin(__builtin_elementwise_fma)
    return __builtin_elementwise_fma(a, b, c);   // -> v_pk_fma_f32
#else
    v2f r; r.x = fmaf(a.x, b.x, c.x); r.y = fmaf(a.y, b.y, c.y); return r;
#endif
}

// ---------------------------------------------------------------------------
// K1: bidirectional LSTM, round 7 restructure.
// Previous version: 8 blocks, 16 lanes/chain, 64 weight floats/lane ->
// VGPR_Count=52 proved the weights NEVER fit in registers; they spilled and
// were re-fetched every timestep (~700 cyc/step, per-CU VALU busy only ~18%).
// New: 16 blocks x 64 threads. Each chain (dir,b) owned by 32 lanes:
//   lane bits: u = lane&15 (unit), half = (lane>>4)&1 (k-half), qb = lane>>5
//   (batch-in-pair). half0 accumulates recurrent terms j=0..7 (+x+bias),
//   half1 accumulates j=8..15. Per-lane weights: 32 floats -> fits in VGPRs.
// h-distribution: rows of 16 lanes each hold a full copy of h (both halves
// redundantly compute identical h,c after the reduction). One ror:8 DPP +
// cndmask gives half1 rows a base pre-rotated by 8 (x^8 == x+8 mod 16), then
// ror:1..7 (all INDEPENDENT, sourced from the base — no serial rotate chain)
// deliver h[(u-j)&15] for this lane's j-range. Partial gate sums are combined
// with a single xor-16 ds_swizzle (partner lane = same unit, other k-half).
// Accumulation depth: 2 split accumulators x 4 fma. Weights loaded through a
// volatile pointer so loads execute exactly once (values then live in VGPRs —
// and now they FIT).
// ---------------------------------------------------------------------------
__global__ __launch_bounds__(64, 1) void k1_lstm(
    const float* __restrict__ sent,   // [B,T]
    const float* __restrict__ h0,     // [2,B,16]
    const float* __restrict__ c0,     // [2,B,16]
    const float* __restrict__ Wih_f, const float* __restrict__ Whh_f, const float* __restrict__ b_f,
    const float* __restrict__ Wih_b, const float* __restrict__ Whh_b, const float* __restrict__ b_b)
{
    const int blk   = blockIdx.x;       // 0..15
    const int dir   = blk >> 3;         // 0 fwd, 1 bwd
    const int bpair = blk & 7;          // batch pair
    const int lane  = threadIdx.x;
    const int u     = lane & 15;        // hidden unit
    const int half  = (lane >> 4) & 1;  // k-half: 0 -> j=0..7, 1 -> j=8..15
    const int qb    = lane >> 5;        // batch slot in wave
    const int b     = bpair * 2 + qb;

    volatile const float* Wih  = dir ? Wih_b : Wih_f;
    volatile const float* Whh  = dir ? Whh_b : Whh_f;
    volatile const float* bias = dir ? b_b   : b_f;

    // Per-lane recurrent weights for this lane's j-range (j = 8*half + k):
    // w*[k] multiplies h[(u-j)&15]. Packed: wIF = (i,f), wGO = (g,o).
    const int j0 = half * 8;
    v2f wIF[8], wGO[8];
    #pragma unroll
    for (int k = 0; k < 8; ++k) {
        const int m = (u - (j0 + k)) & 15;
        v2f a, g2;
        a.x  = Whh[(u)      * 16 + m];
        a.y  = Whh[(u + 16) * 16 + m];
        g2.x = Whh[(u + 32) * 16 + m];
        g2.y = Whh[(u + 48) * 16 + m];
        wIF[k] = a;
        wGO[k] = g2;
    }
    // x-weights and bias contribute exactly once per gate: half0 only.
    const float hm = half ? 0.0f : 1.0f;
    v2f wxIF, wxGO, bIF2, bGO2;
    wxIF.x = Wih[u]      * hm; wxIF.y = Wih[u + 16] * hm;
    wxGO.x = Wih[u + 32] * hm; wxGO.y = Wih[u + 48] * hm;
    bIF2.x = bias[u]      * hm; bIF2.y = bias[u + 16] * hm;
    bGO2.x = bias[u + 32] * hm; bGO2.y = bias[u + 48] * hm;

    // per-lane state (identical across the two halves of a chain)
    float hn = h0[dir * (BATCH * HD) + b * HD + u];
    float c  = c0[dir * (BATCH * HD) + b * HD + u];

    const float* srow = sent + b * TLEN;
    float* obase = g_outBT + (size_t)b * TLEN * HID + dir * HD + u;

    // double-buffered x chunk (4 steps per chunk); bwd consumes reversed
    float4 xc = *(const float4*)(srow + (dir ? (TLEN - 4) : 0));
    for (int tb = 0; tb < TLEN; tb += 4) {
        float4 xn = xc;
        if (tb + 4 < TLEN)
            xn = *(const float4*)(srow + (dir ? (TLEN - 8 - tb) : (tb + 4)));
        float xa[4];
        if (dir) { xa[0] = xc.w; xa[1] = xc.z; xa[2] = xc.y; xa[3] = xc.x; }
        else     { xa[0] = xc.x; xa[1] = xc.y; xa[2] = xc.z; xa[3] = xc.w; }

        #pragma unroll
        for (int s2 = 0; s2 < 4; ++s2) {
            const int t   = tb + s2;
            const int pos = dir ? (TLEN - 1 - t) : t;
            const float x = xa[s2];

            v2f xv; xv.x = x; xv.y = x;
            v2f aIF0 = pk_fma(xv, wxIF, bIF2);
            v2f aGO0 = pk_fma(xv, wxGO, bGO2);
            v2f aIF1; aIF1.x = 0.f; aIF1.y = 0.f;
            v2f aGO1; aGO1.x = 0.f; aGO1.y = 0.f;

            // 8 independent rotations of the row-local h copy.
            const int r0 = __float_as_int(hn);
            const int r8 = __builtin_amdgcn_mov_dpp(r0, 0x128, 0xF, 0xF, true); // ror:8
            const int hb = half ? r8 : r0;   // half1 rows see h pre-rotated by 8
            int rr[8];
            rr[0] = hb;
            rr[1] = __builtin_amdgcn_mov_dpp(hb, 0x121, 0xF, 0xF, true);
            rr[2] = __builtin_amdgcn_mov_dpp(hb, 0x122, 0xF, 0xF, true);
            rr[3] = __builtin_amdgcn_mov_dpp(hb, 0x123, 0xF, 0xF, true);
            rr[4] = __builtin_amdgcn_mov_dpp(hb, 0x124, 0xF, 0xF, true);
            rr[5] = __builtin_amdgcn_mov_dpp(hb, 0x125, 0xF, 0xF, true);
            rr[6] = __builtin_amdgcn_mov_dpp(hb, 0x126, 0xF, 0xF, true);
            rr[7] = __builtin_amdgcn_mov_dpp(hb, 0x127, 0xF, 0xF, true);

            #pragma unroll
            for (int k = 0; k < 8; k += 2) {
                v2f h0v; h0v.x = __int_as_float(rr[k]);     h0v.y = h0v.x;
                v2f h1v; h1v.x = __int_as_float(rr[k + 1]); h1v.y = h1v.x;
                aIF0 = pk_fma(wIF[k],     h0v, aIF0);
                aGO0 = pk_fma(wGO[k],     h0v, aGO0);
                aIF1 = pk_fma(wIF[k + 1], h1v, aIF1);
                aGO1 = pk_fma(wGO[k + 1], h1v, aGO1);
            }
            v2f pIF = aIF0 + aIF1;
            v2f pGO = aGO0 + aGO1;

            // combine the two k-halves: partner = lane ^ 16 (same unit/batch)
            pIF.x += __int_as_float(__builtin_amdgcn_ds_swizzle(__float_as_int(pIF.x), 0x401F));
            pIF.y += __int_as_float(__builtin_amdgcn_ds_swizzle(__float_as_int(pIF.y), 0x401F));
            pGO.x += __int_as_float(__builtin_amdgcn_ds_swizzle(__float_as_int(pGO.x), 0x401F));
            pGO.y += __int_as_float(__builtin_amdgcn_ds_swizzle(__float_as_int(pGO.y), 0x401F));

            const float ai = sigm_(pIF.x), af = sigm_(pIF.y), ao = sigm_(pGO.y);
            const float ag = tanh_(pGO.x);
            c = fmaf(af, c, ai * ag);
            hn = ao * tanh_(c);

            if (half == 0)
                obase[(size_t)pos * HID] = hn;
        }
        xc = xn;
    }
}

// ---------------------------------------------------------------------------
// K2: projections. Thread per (b,t). W1 etc. staged in LDS.
//   preA[b][t][h] = out[b,t,:] . W1[h,0:32]  + b1[h]
//   Ct  [b][h][t] = out[b,t,:] . W1[h,32:64]           (transposed for K34)
//   un  [b][t]    = out . Wu + bu
//   w2d [b][t]    = out . Wout
// ---------------------------------------------------------------------------
__global__ __launch_bounds__(256) void k2_proj(
    const float* __restrict__ W1,     // [32,64]
    const float* __restrict__ b1,     // [32]
    const float* __restrict__ Wu,     // [32]
    const float* __restrict__ bu,     // [1]
    const float* __restrict__ Wout)   // [32]
{
    __shared__ float w1s[HID * 64];
    __shared__ float b1s[HID], wus[HID], wos[HID];
    const int tid = threadIdx.x;
    for (int k = tid; k < HID * 64; k += 256) w1s[k] = W1[k];
    if (tid < HID) { b1s[tid] = b1[tid]; wus[tid] = Wu[tid]; wos[tid] = Wout[tid]; }
    __syncthreads();

    const int g = blockIdx.x * 256 + tid;    // 0..8191
    const int b = g >> 9;
    const int t = g & (TLEN - 1);

    float o[32];
    const float4* src = (const float4*)(g_outBT + (size_t)g * HID);
    #pragma unroll
    for (int qq = 0; qq < 8; ++qq) {
        float4 v = src[qq];
        o[qq * 4 + 0] = v.x; o[qq * 4 + 1] = v.y; o[qq * 4 + 2] = v.z; o[qq * 4 + 3] = v.w;
    }

    float* pa = g_preA + (size_t)g * HID;
    float* ct = g_Ct + (size_t)b * HID * TLEN + t;
    #pragma unroll 4
    for (int h = 0; h < HID; ++h) {
        float a = b1s[h], cacc = 0.f;
        const float* wr = &w1s[h * 64];
        #pragma unroll
        for (int k = 0; k < HID; ++k) {
            a    = fmaf(o[k], wr[k], a);
            cacc = fmaf(o[k], wr[32 + k], cacc);
        }
        pa[h] = a;
        ct[(size_t)h * TLEN] = cacc;
    }

    float ua = 0.f, wa = 0.f;
    #pragma unroll
    for (int k = 0; k < HID; ++k) { ua = fmaf(o[k], wus[k], ua); wa = fmaf(o[k], wos[k], wa); }
    g_un[g]  = ua + bu[0];
    g_w2d[g] = wa;
}

// ---------------------------------------------------------------------------
// K34: S[b,i] = sum_j sum_h relu(preA[b,i,h] + Ct[b,h,j]) * W2[h]
//      prob[b,i] = sigmoid((S - diag_i + 511*b2)/100 + un[b,i])
//      out[b] = sum_i prob[b,i]*w2d[b,i] / 512 + bout   (fused, O(1)-atomic tail)
// ---------------------------------------------------------------------------
__global__ __launch_bounds__(256) void k34_binary(
    const float* __restrict__ W2,     // [32]
    const float* __restrict__ b2p,    // [1]
    const float* __restrict__ boutp,  // [1]
    float* __restrict__ out)          // [16]
{
    const int b     = blockIdx.x >> 6;
    const int itile = blockIdx.x & 63;
    const int i0    = itile * 8;
    const int tid   = threadIdx.x;

    __shared__ float pa[8][HID];
    __shared__ float w2s[HID];
    __shared__ float redw[4][8];

    pa[tid >> 5][tid & 31] = g_preA[((size_t)b * TLEN + i0 + (tid >> 5)) * HID + (tid & 31)];
    if (tid < HID) w2s[tid] = W2[tid];
    __syncthreads();

    const float* ctb = g_Ct + (size_t)b * HID * TLEN;
    const int j0 = tid, j1 = tid + 256;

    float acc[8];
    #pragma unroll
    for (int ii = 0; ii < 8; ++ii) acc[ii] = 0.f;

    for (int h = 0; h < HID; ++h) {
        const float c0v = ctb[(size_t)h * TLEN + j0];
        const float c1v = ctb[(size_t)h * TLEN + j1];
        const float w   = w2s[h];
        #pragma unroll
        for (int ii = 0; ii < 8; ++ii) {
            const float p = pa[ii][h];
            acc[ii] = fmaf(fmaxf(p + c0v, 0.f), w, acc[ii]);
            acc[ii] = fmaf(fmaxf(p + c1v, 0.f), w, acc[ii]);
        }
    }

    #pragma unroll
    for (int ii = 0; ii < 8; ++ii) {
        float v = acc[ii];
        #pragma unroll
        for (int off = 32; off >= 1; off >>= 1) v += __shfl_down(v, off);
        if ((tid & 63) == 0) redw[tid >> 6][ii] = v;
    }
    __syncthreads();

    if (tid < 8) {
        const float S = redw[0][tid] + redw[1][tid] + redw[2][tid] + redw[3][tid];
        const int i = i0 + tid;
        float diag = 0.f;
        #pragma unroll
        for (int h = 0; h < HID; ++h)
            diag = fmaf(fmaxf(pa[tid][h] + ctb[(size_t)h * TLEN + i], 0.f), w2s[h], diag);
        const float b2 = b2p[0];
        const float s = (S - diag + (float)(TLEN - 1) * b2) * 0.01f + g_un[(size_t)b * TLEN + i];
        float contrib = sigm_(s) * g_w2d[(size_t)b * TLEN + i];
        // reduce 8 lanes (lanes 0..7 of wave 0)
        contrib += __shfl_down(contrib, 4);
        contrib += __shfl_down(contrib, 2);
        contrib += __shfl_down(contrib, 1);
        if (tid == 0) {
            atomicAdd(&g_accum[b], contrib);          // one device-scope atomic
            __threadfence();
            int old = atomicAdd(&g_cnt[b], 1);
            if (old == 63) {                          // last arriver for this b
                __threadfence();
                float tot = atomicExch(&g_accum[b], 0.0f);  // read + reset
                out[b] = tot * (1.0f / (float)TLEN) + boutp[0];
                atomicExch(&g_cnt[b], 0);             // restore for next call
            }
        }
    }
}

extern "C" void kernel_launch(void* const* d_in, const int* in_sizes, int n_in,
                              void* d_out, int out_size, void* d_ws, size_t ws_size,
                              hipStream_t stream) {
    const float* sent  = (const float*)d_in[0];
    const float* h0    = (const float*)d_in[1];
    const float* c0    = (const float*)d_in[2];
    const float* Wih_f = (const float*)d_in[3];
    const float* Whh_f = (const float*)d_in[4];
    const float* b_f   = (const float*)d_in[5];
    const float* Wih_b = (const float*)d_in[6];
    const float* Whh_b = (const float*)d_in[7];
    const float* b_b   = (const float*)d_in[8];
    const float* W1    = (const float*)d_in[9];
    const float* b1    = (const float*)d_in[10];
    const float* W2    = (const float*)d_in[11];
    const float* b2    = (const float*)d_in[12];
    const float* Wu    = (const float*)d_in[13];
    const float* bu    = (const float*)d_in[14];
    const float* Wout  = (const float*)d_in[15];
    const float* bout  = (const float*)d_in[16];

    k1_lstm<<<16, 64, 0, stream>>>(sent, h0, c0, Wih_f, Whh_f, b_f,
                                   Wih_b, Whh_b, b_b);
    k2_proj<<<32, 256, 0, stream>>>(W1, b1, Wu, bu, Wout);
    k34_binary<<<1024, 256, 0, stream>>>(W2, b2, bout, (float*)d_out);
}